// Round 1
// baseline (617.026 us; speedup 1.0000x reference)
//
#include <hip/hip_runtime.h>

typedef unsigned int  u32;
typedef unsigned short u16;
typedef __attribute__((ext_vector_type(8))) short short8;
typedef __attribute__((ext_vector_type(4))) float f32x4;

#define CI 64
#define CO 128
#define HH 128
#define WW 128
#define HO 126
#define WO 126

// round-to-nearest-even fp32 -> bf16 (bits)
__device__ __forceinline__ u16 f2bf(float f) {
    u32 u = __builtin_bit_cast(u32, f);
    u = (u + 0x7FFFu + ((u >> 16) & 1u)) >> 16;
    return (u16)u;
}

// ---- kernel 1: reorder weights (C_out,C_in,3,3) fp32 -> [tap][co][ci] bf16 ----
__global__ void reorder_w(const float* __restrict__ w, u16* __restrict__ wq) {
    int i = blockIdx.x * 256 + threadIdx.x;     // 9*128*64 = 73728
    if (i < 9 * CO * CI) {
        int ci  = i & 63;
        int co  = (i >> 6) & 127;
        int tap = i >> 13;
        wq[i] = f2bf(w[(co * CI + ci) * 9 + tap]);
    }
}

// ---- kernel 2 (fast path): x fp32 NCHW -> bf16 swizzled-NHWC in ws ----
// v3: coalesced reads + LDS transpose (old version did 64KB-strided gathers).
// Global layout out: xq[(n*128+h)*8192 + w*64 + slot*8 + j], ci = (slot^(w&7))*8 + j.
// LDS tile: lf[ci*128 + ((w4 ^ s(ci))*4) + (w&3)], s(ci) = (ci>>3)^(ci&7).
//  - write phase: per-ci rows stay contiguous (permuted float4s) -> conflict-free b128 writes
//  - read phase: banks = 4*((w4^g^j)&7) + (w&3) -> max 2-way (free)
__global__ __launch_bounds__(256)
void prep_x(const float* __restrict__ x, u16* __restrict__ xq) {
    __shared__ float lf[64 * 128];         // 32 KB
    const int row = blockIdx.x;            // n*128 + h, 4096 rows
    const int n = row >> 7, h = row & 127;
    const float* xb = x + (size_t)n * CI * HH * WW + (size_t)h * WW;

    const int w4  = threadIdx.x & 31;      // float4 index along w
    const int ci0 = threadIdx.x >> 5;      // 0..7
#pragma unroll
    for (int it = 0; it < 8; ++it) {
        int ci = it * 8 + ci0;
        f32x4 v = *(const f32x4*)(xb + (size_t)ci * (HH * WW) + w4 * 4);  // 512B/row segs, coalesced
        int s = (ci >> 3) ^ (ci & 7);
        *(f32x4*)&lf[ci * 128 + ((w4 ^ s) * 4)] = v;
    }
    __syncthreads();

    u16* dst = xq + (size_t)row * 8192;
#pragma unroll
    for (int it = 0; it < 4; ++it) {
        int idx  = it * 256 + threadIdx.x; // 1024 = 128 w * 8 slots
        int slot = idx & 7;
        int w    = idx >> 3;
        int g    = slot ^ (w & 7);
        int wq4  = w >> 2, wr = w & 3;
        u32 parts[4];
#pragma unroll
        for (int jj = 0; jj < 4; ++jj) {
            int ca = g * 8 + 2 * jj;
            int cb = ca + 1;
            float va = lf[ca * 128 + ((wq4 ^ ((ca >> 3) ^ (ca & 7))) * 4) + wr];
            float vb = lf[cb * 128 + ((wq4 ^ ((cb >> 3) ^ (cb & 7))) * 4) + wr];
            parts[jj] = (u32)f2bf(va) | ((u32)f2bf(vb) << 16);
        }
        uint4 q;
        q.x = parts[0]; q.y = parts[1]; q.z = parts[2]; q.w = parts[3];
        *(uint4*)(dst + (size_t)w * 64 + slot * 8) = q;   // coalesced 16B/lane
    }
}

// shared epilogue: bias + mish + BN affine, writes one output row for one acc set
__device__ __forceinline__ void epilog(const f32x4 (&acc)[4][4], float* __restrict__ ob,
                                       int wn, int li, int wm, int qd,
                                       const float* s_scale, const float* s_shift,
                                       const float* s_bias) {
#pragma unroll
    for (int j = 0; j < 4; ++j) {
        int wo = wn * 64 + j * 16 + li;
        if (wo < WO) {
#pragma unroll
            for (int i = 0; i < 4; ++i) {
#pragma unroll
                for (int r = 0; r < 4; ++r) {
                    int co  = wm * 64 + i * 16 + qd * 4 + r;      // C/D row = quad*4+reg
                    float z  = acc[i][j][r] + s_bias[co];
                    float u  = 1.0f + __expf(fminf(z, 20.0f));
                    float u2 = u * u;
                    float t  = __fdividef(u2 - 1.0f, u2 + 1.0f);  // tanh(softplus(z))
                    ob[(size_t)co * (HO * WO) + wo] = z * t * s_scale[co] + s_shift[co];
                }
            }
        }
    }
}

// ---- kernel 3 (fast path): conv via implicit GEMM, 2 output rows / block ----
// 4 input rows staged per block (64 KB); b-fragments loaded once per input row
// and reused for both output rows' accumulators. Tap order per output matches
// v2 exactly (kh,kw,ks) -> bit-identical sums.
__global__ __launch_bounds__(256, 2)
void conv_mfma_v3(const u16* __restrict__ xq, const u16* __restrict__ wq,
                  const float* __restrict__ bias, const float* __restrict__ gamma,
                  const float* __restrict__ beta, const float* __restrict__ rmean,
                  const float* __restrict__ rvar, float* __restrict__ out) {
    __shared__ u16 in_lds[4 * 128 * 64];   // 64 KB, rows h0..h0+3, swizzled layout
    __shared__ float s_scale[CO], s_shift[CO], s_bias[CO];

    const int tid = threadIdx.x;
    const int h0  = blockIdx.x * 2;   // 0,2,..,124
    const int n   = blockIdx.y;       // 0..31

    // DMA rows h0..h0+3 (contiguous 64 KB in xq) into LDS: 16 x 1KB per wave.
    const int wv   = tid >> 6;
    const int lane = tid & 63;
    const u16* src = xq + (size_t)(n * 128 + h0) * 8192;
#pragma unroll
    for (int s = 0; s < 16; ++s) {
        int chunk = s * 4 + wv;                      // 64 chunks of 512 u16 (1 KB)
        const u16* gp = src + chunk * 512 + lane * 8;
        u16*       lp = in_lds + chunk * 512 + lane * 8;
        __builtin_amdgcn_global_load_lds(
            (const __attribute__((address_space(1))) u32*)gp,
            (__attribute__((address_space(3))) u32*)lp, 16, 0, 0);
    }

    if (tid < CO) {                                  // overlaps DMA latency
        float sc = gamma[tid] * rsqrtf(rvar[tid] + 1e-5f);
        s_scale[tid] = sc;
        s_shift[tid] = beta[tid] - rmean[tid] * sc;
        s_bias[tid]  = bias[tid];
    }
    __syncthreads();

    const int li = tid & 15;          // lane & 15
    const int qd = (tid & 63) >> 4;   // quad
    const int wm = wv & 1;            // m-half (c_out)
    const int wn = wv >> 1;           // n-half (pixels)

    f32x4 zero4 = {0.f, 0.f, 0.f, 0.f};
    f32x4 acc0[4][4], acc1[4][4];
#pragma unroll
    for (int i = 0; i < 4; ++i)
#pragma unroll
        for (int j = 0; j < 4; ++j) { acc0[i][j] = zero4; acc1[i][j] = zero4; }

    const uint4* wg = (const uint4*)wq;   // [tap][co][g] 16B granules

    // input-row loop: row r feeds out-row0 at kh=r (r<3) and out-row1 at kh=r-1 (r>=1)
#pragma unroll 1
    for (int r = 0; r < 4; ++r) {
#pragma unroll
        for (int kw = 0; kw < 3; ++kw) {
#pragma unroll
            for (int ks = 0; ks < 2; ++ks) {
                short8 b[4];
#pragma unroll
                for (int j = 0; j < 4; ++j) {
                    int w = wn * 64 + j * 16 + li + kw;   // <=129; OOB lanes masked in epilogue
                    int g = ks * 4 + qd;                  // ci group
                    b[j] = *(const short8*)&in_lds[(size_t)(r * 128 + w) * 64 +
                                                   ((g ^ (w & 7)) * 8)];
                }
                if (r < 3) {
                    const int tap = r * 3 + kw;
                    short8 a[4];
#pragma unroll
                    for (int i = 0; i < 4; ++i) {
                        int co = wm * 64 + i * 16 + li;
                        a[i] = __builtin_bit_cast(short8,
                            wg[tap * 1024 + co * 8 + ks * 4 + qd]);
                    }
#pragma unroll
                    for (int i = 0; i < 4; ++i)
#pragma unroll
                        for (int j = 0; j < 4; ++j)
                            acc0[i][j] = __builtin_amdgcn_mfma_f32_16x16x32_bf16(
                                a[i], b[j], acc0[i][j], 0, 0, 0);
                }
                if (r >= 1) {
                    const int tap = (r - 1) * 3 + kw;
                    short8 a[4];
#pragma unroll
                    for (int i = 0; i < 4; ++i) {
                        int co = wm * 64 + i * 16 + li;
                        a[i] = __builtin_bit_cast(short8,
                            wg[tap * 1024 + co * 8 + ks * 4 + qd]);
                    }
#pragma unroll
                    for (int i = 0; i < 4; ++i)
#pragma unroll
                        for (int j = 0; j < 4; ++j)
                            acc1[i][j] = __builtin_amdgcn_mfma_f32_16x16x32_bf16(
                                a[i], b[j], acc1[i][j], 0, 0, 0);
                }
            }
        }
    }

    float* ob = out + (size_t)n * CO * (HO * WO) + (size_t)h0 * WO;
    epilog(acc0, ob,      wn, li, wm, qd, s_scale, s_shift, s_bias);
    epilog(acc1, ob + WO, wn, li, wm, qd, s_scale, s_shift, s_bias);
}

// ---- fallback (round-1) conv: used only if ws too small for xq ----
__global__ __launch_bounds__(256, 2)
void conv_mfma(const float* __restrict__ x, const u16* __restrict__ wq,
               const float* __restrict__ bias, const float* __restrict__ gamma,
               const float* __restrict__ beta, const float* __restrict__ rmean,
               const float* __restrict__ rvar, float* __restrict__ out) {
    __shared__ u32 in_lds[3 * 130 * 32];
    __shared__ float s_scale[CO], s_shift[CO], s_bias[CO];

    const int tid = threadIdx.x;
    const int h0  = blockIdx.x;
    const int n   = blockIdx.y;

    if (tid < CO) {
        float sc = gamma[tid] * rsqrtf(rvar[tid] + 1e-5f);
        s_scale[tid] = sc;
        s_shift[tid] = beta[tid] - rmean[tid] * sc;
        s_bias[tid]  = bias[tid];
    }
    if (tid < 48) {
        int kh  = tid >> 4;
        int rem = tid & 15;
        int w   = 128 + (rem & 1);
        int g   = rem >> 1;
        uint4 z = {0u, 0u, 0u, 0u};
        *(uint4*)&in_lds[(kh * 130 + w) * 32 + ((g ^ (w & 7)) * 4)] = z;
    }
    const float* xb = x + (size_t)n * CI * HH * WW;
    for (int it = 0; it < 12; ++it) {
        int idx = it * 256 + tid;
        int w   = idx & 127;
        int g   = (idx >> 7) & 7;
        int kh  = idx >> 10;
        const float* p = xb + (g * 8) * (HH * WW) + (h0 + kh) * WW + w;
        float v[8];
#pragma unroll
        for (int j = 0; j < 8; ++j) v[j] = p[j * (HH * WW)];
        uint4 q;
        q.x = (u32)f2bf(v[0]) | ((u32)f2bf(v[1]) << 16);
        q.y = (u32)f2bf(v[2]) | ((u32)f2bf(v[3]) << 16);
        q.z = (u32)f2bf(v[4]) | ((u32)f2bf(v[5]) << 16);
        q.w = (u32)f2bf(v[6]) | ((u32)f2bf(v[7]) << 16);
        *(uint4*)&in_lds[(kh * 130 + w) * 32 + ((g ^ (w & 7)) * 4)] = q;
    }
    __syncthreads();

    const int wv = tid >> 6;
    const int li = tid & 15;
    const int qd = (tid & 63) >> 4;
    const int wm = wv & 1;
    const int wn = wv >> 1;

    f32x4 zero4 = {0.f, 0.f, 0.f, 0.f};
    f32x4 acc[4][4];
#pragma unroll
    for (int i = 0; i < 4; ++i)
#pragma unroll
        for (int j = 0; j < 4; ++j) acc[i][j] = zero4;

    const uint4* wg = (const uint4*)wq;

#pragma unroll 1
    for (int kh = 0; kh < 3; ++kh) {
#pragma unroll
        for (int kw = 0; kw < 3; ++kw) {
            const int tap = kh * 3 + kw;
#pragma unroll
            for (int ks = 0; ks < 2; ++ks) {
                short8 a[4], b[4];
#pragma unroll
                for (int i = 0; i < 4; ++i) {
                    int co = wm * 64 + i * 16 + li;
                    a[i] = __builtin_bit_cast(short8,
                        wg[tap * 1024 + co * 8 + ks * 4 + qd]);
                }
#pragma unroll
                for (int j = 0; j < 4; ++j) {
                    int w = wn * 64 + j * 16 + li + kw;
                    int g = ks * 4 + qd;
                    b[j] = *(const short8*)&in_lds[(kh * 130 + w) * 32 +
                                                   ((g ^ (w & 7)) * 4)];
                }
#pragma unroll
                for (int i = 0; i < 4; ++i)
#pragma unroll
                    for (int j = 0; j < 4; ++j)
                        acc[i][j] = __builtin_amdgcn_mfma_f32_16x16x32_bf16(
                            a[i], b[j], acc[i][j], 0, 0, 0);
            }
        }
    }

    float* ob = out + (size_t)n * CO * (HO * WO) + (size_t)h0 * WO;
#pragma unroll
    for (int j = 0; j < 4; ++j) {
        int wo = wn * 64 + j * 16 + li;
        if (wo < WO) {
#pragma unroll
            for (int i = 0; i < 4; ++i) {
#pragma unroll
                for (int r = 0; r < 4; ++r) {
                    int co  = wm * 64 + i * 16 + qd * 4 + r;
                    float z  = acc[i][j][r] + s_bias[co];
                    float u  = 1.0f + __expf(fminf(z, 20.0f));
                    float u2 = u * u;
                    float t  = __fdividef(u2 - 1.0f, u2 + 1.0f);
                    ob[(size_t)co * (HO * WO) + wo] = z * t * s_scale[co] + s_shift[co];
                }
            }
        }
    }
}

extern "C" void kernel_launch(void* const* d_in, const int* in_sizes, int n_in,
                              void* d_out, int out_size, void* d_ws, size_t ws_size,
                              hipStream_t stream) {
    const float* x     = (const float*)d_in[0];
    const float* wt    = (const float*)d_in[1];
    const float* bias  = (const float*)d_in[2];
    const float* gamma = (const float*)d_in[3];
    const float* beta  = (const float*)d_in[4];
    const float* rmean = (const float*)d_in[5];
    const float* rvar  = (const float*)d_in[6];

    const size_t XQ_BYTES = (size_t)64 * 1024 * 1024;    // 32*128*128*64*2 = 64 MiB
    const size_t WQ_BYTES = (size_t)9 * CO * CI * 2;     // 144 KiB

    if (ws_size >= XQ_BYTES + WQ_BYTES) {
        u16* xq = (u16*)d_ws;
        u16* wq = (u16*)((char*)d_ws + XQ_BYTES);
        hipLaunchKernelGGL(reorder_w, dim3(288), dim3(256), 0, stream, wt, wq);
        hipLaunchKernelGGL(prep_x, dim3(4096), dim3(256), 0, stream, x, xq);
        hipLaunchKernelGGL(conv_mfma_v3, dim3(HO / 2, 32), dim3(256), 0, stream,
                           xq, wq, bias, gamma, beta, rmean, rvar, (float*)d_out);
    } else {
        u16* wq = (u16*)d_ws;
        hipLaunchKernelGGL(reorder_w, dim3(288), dim3(256), 0, stream, wt, wq);
        hipLaunchKernelGGL(conv_mfma, dim3(HO, 32), dim3(256), 0, stream,
                           x, wq, bias, gamma, beta, rmean, rvar, (float*)d_out);
    }
}

// Round 2
// 526.595 us; speedup vs baseline: 1.1717x; 1.1717x over previous
//
#include <hip/hip_runtime.h>

typedef unsigned int  u32;
typedef unsigned short u16;
typedef __attribute__((ext_vector_type(8))) short short8;
typedef __attribute__((ext_vector_type(4))) float f32x4;

#define CI 64
#define CO 128
#define HH 128
#define WW 128
#define HO 126
#define WO 126

// round-to-nearest-even fp32 -> bf16 (bits)
__device__ __forceinline__ u16 f2bf(float f) {
    u32 u = __builtin_bit_cast(u32, f);
    u = (u + 0x7FFFu + ((u >> 16) & 1u)) >> 16;
    return (u16)u;
}

// ---- kernel 1: reorder weights (C_out,C_in,3,3) fp32 -> [tap][co][ci] bf16 ----
__global__ void reorder_w(const float* __restrict__ w, u16* __restrict__ wq) {
    int i = blockIdx.x * 256 + threadIdx.x;     // 9*128*64 = 73728
    if (i < 9 * CO * CI) {
        int ci  = i & 63;
        int co  = (i >> 6) & 127;
        int tap = i >> 13;
        wq[i] = f2bf(w[(co * CI + ci) * 9 + tap]);
    }
}

// ---- kernel 2 (fast path): x fp32 NCHW -> bf16 swizzled-NHWC in ws ----
// Coalesced reads + LDS transpose.
// Global layout out: xq[(n*128+h)*8192 + w*64 + slot*8 + j], ci = (slot^(w&7))*8 + j.
__global__ __launch_bounds__(256)
void prep_x(const float* __restrict__ x, u16* __restrict__ xq) {
    __shared__ float lf[64 * 128];         // 32 KB
    const int row = blockIdx.x;            // n*128 + h, 4096 rows
    const int n = row >> 7, h = row & 127;
    const float* xb = x + (size_t)n * CI * HH * WW + (size_t)h * WW;

    const int w4  = threadIdx.x & 31;      // float4 index along w
    const int ci0 = threadIdx.x >> 5;      // 0..7
#pragma unroll
    for (int it = 0; it < 8; ++it) {
        int ci = it * 8 + ci0;
        f32x4 v = *(const f32x4*)(xb + (size_t)ci * (HH * WW) + w4 * 4);  // coalesced
        int s = (ci >> 3) ^ (ci & 7);
        *(f32x4*)&lf[ci * 128 + ((w4 ^ s) * 4)] = v;
    }
    __syncthreads();

    u16* dst = xq + (size_t)row * 8192;
#pragma unroll
    for (int it = 0; it < 4; ++it) {
        int idx  = it * 256 + threadIdx.x; // 1024 = 128 w * 8 slots
        int slot = idx & 7;
        int w    = idx >> 3;
        int g    = slot ^ (w & 7);
        int wq4  = w >> 2, wr = w & 3;
        u32 parts[4];
#pragma unroll
        for (int jj = 0; jj < 4; ++jj) {
            int ca = g * 8 + 2 * jj;
            int cb = ca + 1;
            float va = lf[ca * 128 + ((wq4 ^ ((ca >> 3) ^ (ca & 7))) * 4) + wr];
            float vb = lf[cb * 128 + ((wq4 ^ ((cb >> 3) ^ (cb & 7))) * 4) + wr];
            parts[jj] = (u32)f2bf(va) | ((u32)f2bf(vb) << 16);
        }
        uint4 q;
        q.x = parts[0]; q.y = parts[1]; q.z = parts[2]; q.w = parts[3];
        *(uint4*)(dst + (size_t)w * 64 + slot * 8) = q;   // coalesced 16B/lane
    }
}

// ---- kernel 3 (fast path): conv via implicit GEMM, DMA staging ----
// v4 = round-0 v2 structure (proven 235us: 48KB LDS, 3 blocks/CU) plus:
//  * swapped MFMA operands: D rows = wo, D cols = co -> each lane's 4 acc regs
//    are 4 consecutive wo of ONE co => vectorized stores (float4 / 2x float2),
//    scale/bias fetched once per i (shared across the 4 regs).
//  * XCD-chunk block swizzle: 4032 blocks = 8 XCDs x 504; consecutive h on the
//    same XCD -> the 2-of-3 staged-row overlap becomes same-L2 hits.
__global__ __launch_bounds__(256, 2)
void conv_mfma_v4(const u16* __restrict__ xq, const u16* __restrict__ wq,
                  const float* __restrict__ bias, const float* __restrict__ gamma,
                  const float* __restrict__ beta, const float* __restrict__ rmean,
                  const float* __restrict__ rvar, float* __restrict__ out) {
    __shared__ u16 in_lds[3 * 128 * 64];   // 48 KB, rows h0..h0+2, swizzled layout
    __shared__ float s_scale[CO], s_shift[CO], s_bias[CO];

    const int tid = threadIdx.x;
    // bijective XCD swizzle: dispatch id D -> work id L, XCD (D&7) gets chunk of 504
    const int D = blockIdx.y * 126 + blockIdx.x;
    const int L = (D & 7) * 504 + (D >> 3);
    const int n  = L / 126;          // 0..31
    const int h0 = L - n * 126;      // 0..125

    // DMA rows h0..h0+2 (contiguous 48 KB in xq) into LDS: 12 x 1KB per wave.
    const int wv   = tid >> 6;
    const int lane = tid & 63;
    const u16* src = xq + (size_t)(n * 128 + h0) * 8192;
#pragma unroll
    for (int s = 0; s < 12; ++s) {
        int chunk = s * 4 + wv;                      // 48 chunks of 512 u16 (1 KB)
        const u16* gp = src + chunk * 512 + lane * 8;
        u16*       lp = in_lds + chunk * 512 + lane * 8;
        __builtin_amdgcn_global_load_lds(
            (const __attribute__((address_space(1))) u32*)gp,
            (__attribute__((address_space(3))) u32*)lp, 16, 0, 0);
    }

    if (tid < CO) {                                  // VALU work overlaps DMA latency
        float sc = gamma[tid] * rsqrtf(rvar[tid] + 1e-5f);
        s_scale[tid] = sc;
        s_shift[tid] = beta[tid] - rmean[tid] * sc;
        s_bias[tid]  = bias[tid];
    }
    __syncthreads();

    const int li = tid & 15;          // lane & 15
    const int qd = (tid & 63) >> 4;   // quad
    const int wm = wv & 1;            // co-half
    const int wn = wv >> 1;           // pixel-half

    f32x4 zero4 = {0.f, 0.f, 0.f, 0.f};
    f32x4 acc[4][4];
#pragma unroll
    for (int i = 0; i < 4; ++i)
#pragma unroll
        for (int j = 0; j < 4; ++j) acc[i][j] = zero4;

    const uint4* wg = (const uint4*)wq;   // [tap][co][g] 16B granules

    // barrier-free K-loop: 9 taps x 2 K-steps of 32
#pragma unroll 1
    for (int kh = 0; kh < 3; ++kh) {
#pragma unroll
        for (int kw = 0; kw < 3; ++kw) {
            const int tap = kh * 3 + kw;
#pragma unroll
            for (int ks = 0; ks < 2; ++ks) {
                short8 a[4], b[4];
#pragma unroll
                for (int i = 0; i < 4; ++i) {
                    int co = wm * 64 + i * 16 + li;
                    a[i] = __builtin_bit_cast(short8,
                        wg[tap * 1024 + co * 8 + ks * 4 + qd]);   // weights (L2)
                }
#pragma unroll
                for (int j = 0; j < 4; ++j) {
                    int w = wn * 64 + j * 16 + li + kw;           // input col
                    int g = ks * 4 + qd;                          // ci group
                    b[j] = *(const short8*)&in_lds[(size_t)(kh * 128 + w) * 64 +
                                                   ((g ^ (w & 7)) * 8)];
                }
                // SWAPPED operands: A=pixels, B=weights => D row=wo, col=co
#pragma unroll
                for (int i = 0; i < 4; ++i)
#pragma unroll
                    for (int j = 0; j < 4; ++j)
                        acc[i][j] = __builtin_amdgcn_mfma_f32_16x16x32_bf16(
                            b[j], a[i], acc[i][j], 0, 0, 0);
            }
        }
    }

    // epilogue: bias + mish + BN affine; vectorized stores (lane owns 4 wo of 1 co)
    const bool al16 = ((h0 & 1) == 0);   // even row base is 16B aligned
    float* ob = out + (size_t)n * CO * (HO * WO) + (size_t)h0 * WO;
#pragma unroll
    for (int i = 0; i < 4; ++i) {
        int co = wm * 64 + i * 16 + li;
        float sc = s_scale[co], sh = s_shift[co], bs = s_bias[co];
        float* op = ob + (size_t)co * (HO * WO);
#pragma unroll
        for (int j = 0; j < 4; ++j) {
            int wo0 = wn * 64 + j * 16 + qd * 4;
            f32x4 v;
#pragma unroll
            for (int r = 0; r < 4; ++r) {
                float z  = acc[i][j][r] + bs;
                float u  = 1.0f + __expf(fminf(z, 20.0f));
                float u2 = u * u;
                float t  = __fdividef(u2 - 1.0f, u2 + 1.0f);  // tanh(softplus(z))
                v[r] = z * t * sc + sh;
            }
            if (wo0 + 3 < WO) {
                if (al16) {
                    *(f32x4*)(op + wo0) = v;
                } else {
                    float2 t0; t0.x = v[0]; t0.y = v[1];
                    float2 t1; t1.x = v[2]; t1.y = v[3];
                    *(float2*)(op + wo0)     = t0;
                    *(float2*)(op + wo0 + 2) = t1;
                }
            } else {
#pragma unroll
                for (int r = 0; r < 4; ++r)
                    if (wo0 + r < WO) op[wo0 + r] = v[r];
            }
        }
    }
}

// ---- fallback (round-1) conv: used only if ws too small for xq ----
__global__ __launch_bounds__(256, 2)
void conv_mfma(const float* __restrict__ x, const u16* __restrict__ wq,
               const float* __restrict__ bias, const float* __restrict__ gamma,
               const float* __restrict__ beta, const float* __restrict__ rmean,
               const float* __restrict__ rvar, float* __restrict__ out) {
    __shared__ u32 in_lds[3 * 130 * 32];
    __shared__ float s_scale[CO], s_shift[CO], s_bias[CO];

    const int tid = threadIdx.x;
    const int h0  = blockIdx.x;
    const int n   = blockIdx.y;

    if (tid < CO) {
        float sc = gamma[tid] * rsqrtf(rvar[tid] + 1e-5f);
        s_scale[tid] = sc;
        s_shift[tid] = beta[tid] - rmean[tid] * sc;
        s_bias[tid]  = bias[tid];
    }
    if (tid < 48) {
        int kh  = tid >> 4;
        int rem = tid & 15;
        int w   = 128 + (rem & 1);
        int g   = rem >> 1;
        uint4 z = {0u, 0u, 0u, 0u};
        *(uint4*)&in_lds[(kh * 130 + w) * 32 + ((g ^ (w & 7)) * 4)] = z;
    }
    const float* xb = x + (size_t)n * CI * HH * WW;
    for (int it = 0; it < 12; ++it) {
        int idx = it * 256 + tid;
        int w   = idx & 127;
        int g   = (idx >> 7) & 7;
        int kh  = idx >> 10;
        const float* p = xb + (g * 8) * (HH * WW) + (h0 + kh) * WW + w;
        float v[8];
#pragma unroll
        for (int j = 0; j < 8; ++j) v[j] = p[j * (HH * WW)];
        uint4 q;
        q.x = (u32)f2bf(v[0]) | ((u32)f2bf(v[1]) << 16);
        q.y = (u32)f2bf(v[2]) | ((u32)f2bf(v[3]) << 16);
        q.z = (u32)f2bf(v[4]) | ((u32)f2bf(v[5]) << 16);
        q.w = (u32)f2bf(v[6]) | ((u32)f2bf(v[7]) << 16);
        *(uint4*)&in_lds[(kh * 130 + w) * 32 + ((g ^ (w & 7)) * 4)] = q;
    }
    __syncthreads();

    const int wv = tid >> 6;
    const int li = tid & 15;
    const int qd = (tid & 63) >> 4;
    const int wm = wv & 1;
    const int wn = wv >> 1;

    f32x4 zero4 = {0.f, 0.f, 0.f, 0.f};
    f32x4 acc[4][4];
#pragma unroll
    for (int i = 0; i < 4; ++i)
#pragma unroll
        for (int j = 0; j < 4; ++j) acc[i][j] = zero4;

    const uint4* wg = (const uint4*)wq;

#pragma unroll 1
    for (int kh = 0; kh < 3; ++kh) {
#pragma unroll
        for (int kw = 0; kw < 3; ++kw) {
            const int tap = kh * 3 + kw;
#pragma unroll
            for (int ks = 0; ks < 2; ++ks) {
                short8 a[4], b[4];
#pragma unroll
                for (int i = 0; i < 4; ++i) {
                    int co = wm * 64 + i * 16 + li;
                    a[i] = __builtin_bit_cast(short8,
                        wg[tap * 1024 + co * 8 + ks * 4 + qd]);
                }
#pragma unroll
                for (int j = 0; j < 4; ++j) {
                    int w = wn * 64 + j * 16 + li + kw;
                    int g = ks * 4 + qd;
                    b[j] = *(const short8*)&in_lds[(kh * 130 + w) * 32 +
                                                   ((g ^ (w & 7)) * 4)];
                }
#pragma unroll
                for (int i = 0; i < 4; ++i)
#pragma unroll
                    for (int j = 0; j < 4; ++j)
                        acc[i][j] = __builtin_amdgcn_mfma_f32_16x16x32_bf16(
                            a[i], b[j], acc[i][j], 0, 0, 0);
            }
        }
    }

    float* ob = out + (size_t)n * CO * (HO * WO) + (size_t)h0 * WO;
#pragma unroll
    for (int j = 0; j < 4; ++j) {
        int wo = wn * 64 + j * 16 + li;
        if (wo < WO) {
#pragma unroll
            for (int i = 0; i < 4; ++i) {
#pragma unroll
                for (int r = 0; r < 4; ++r) {
                    int co  = wm * 64 + i * 16 + qd * 4 + r;
                    float z  = acc[i][j][r] + s_bias[co];
                    float u  = 1.0f + __expf(fminf(z, 20.0f));
                    float u2 = u * u;
                    float t  = __fdividef(u2 - 1.0f, u2 + 1.0f);
                    ob[(size_t)co * (HO * WO) + wo] = z * t * s_scale[co] + s_shift[co];
                }
            }
        }
    }
}

extern "C" void kernel_launch(void* const* d_in, const int* in_sizes, int n_in,
                              void* d_out, int out_size, void* d_ws, size_t ws_size,
                              hipStream_t stream) {
    const float* x     = (const float*)d_in[0];
    const float* wt    = (const float*)d_in[1];
    const float* bias  = (const float*)d_in[2];
    const float* gamma = (const float*)d_in[3];
    const float* beta  = (const float*)d_in[4];
    const float* rmean = (const float*)d_in[5];
    const float* rvar  = (const float*)d_in[6];

    const size_t XQ_BYTES = (size_t)64 * 1024 * 1024;    // 32*128*128*64*2 = 64 MiB
    const size_t WQ_BYTES = (size_t)9 * CO * CI * 2;     // 144 KiB

    if (ws_size >= XQ_BYTES + WQ_BYTES) {
        u16* xq = (u16*)d_ws;
        u16* wq = (u16*)((char*)d_ws + XQ_BYTES);
        hipLaunchKernelGGL(reorder_w, dim3(288), dim3(256), 0, stream, wt, wq);
        hipLaunchKernelGGL(prep_x, dim3(4096), dim3(256), 0, stream, x, xq);
        hipLaunchKernelGGL(conv_mfma_v4, dim3(HO, 32), dim3(256), 0, stream,
                           xq, wq, bias, gamma, beta, rmean, rvar, (float*)d_out);
    } else {
        u16* wq = (u16*)d_ws;
        hipLaunchKernelGGL(reorder_w, dim3(288), dim3(256), 0, stream, wt, wq);
        hipLaunchKernelGGL(conv_mfma, dim3(HO, 32), dim3(256), 0, stream,
                           x, wq, bias, gamma, beta, rmean, rvar, (float*)d_out);
    }
}

// Round 3
// 521.503 us; speedup vs baseline: 1.1832x; 1.0098x over previous
//
#include <hip/hip_runtime.h>

typedef unsigned int  u32;
typedef unsigned short u16;
typedef __attribute__((ext_vector_type(8))) short short8;
typedef __attribute__((ext_vector_type(4))) float f32x4;

#define CI 64
#define CO 128
#define HH 128
#define WW 128
#define HO 126
#define WO 126

// round-to-nearest-even fp32 -> bf16 (bits)
__device__ __forceinline__ u16 f2bf(float f) {
    u32 u = __builtin_bit_cast(u32, f);
    u = (u + 0x7FFFu + ((u >> 16) & 1u)) >> 16;
    return (u16)u;
}

// ---- kernel 1: reorder weights (C_out,C_in,3,3) fp32 -> [tap][co][ci] bf16 ----
__global__ void reorder_w(const float* __restrict__ w, u16* __restrict__ wq) {
    int i = blockIdx.x * 256 + threadIdx.x;     // 9*128*64 = 73728
    if (i < 9 * CO * CI) {
        int ci  = i & 63;
        int co  = (i >> 6) & 127;
        int tap = i >> 13;
        wq[i] = f2bf(w[(co * CI + ci) * 9 + tap]);
    }
}

// ---- kernel 2 (fast path): x fp32 NCHW -> bf16 swizzled-NHWC in ws ----
// Coalesced reads + LDS transpose.
// Global layout out: xq[(n*128+h)*8192 + w*64 + slot*8 + j], ci = (slot^(w&7))*8 + j.
__global__ __launch_bounds__(256)
void prep_x(const float* __restrict__ x, u16* __restrict__ xq) {
    __shared__ float lf[64 * 128];         // 32 KB
    const int row = blockIdx.x;            // n*128 + h, 4096 rows
    const int n = row >> 7, h = row & 127;
    const float* xb = x + (size_t)n * CI * HH * WW + (size_t)h * WW;

    const int w4  = threadIdx.x & 31;      // float4 index along w
    const int ci0 = threadIdx.x >> 5;      // 0..7
#pragma unroll
    for (int it = 0; it < 8; ++it) {
        int ci = it * 8 + ci0;
        f32x4 v = *(const f32x4*)(xb + (size_t)ci * (HH * WW) + w4 * 4);  // coalesced
        int s = (ci >> 3) ^ (ci & 7);
        *(f32x4*)&lf[ci * 128 + ((w4 ^ s) * 4)] = v;
    }
    __syncthreads();

    u16* dst = xq + (size_t)row * 8192;
#pragma unroll
    for (int it = 0; it < 4; ++it) {
        int idx  = it * 256 + threadIdx.x; // 1024 = 128 w * 8 slots
        int slot = idx & 7;
        int w    = idx >> 3;
        int g    = slot ^ (w & 7);
        int wq4  = w >> 2, wr = w & 3;
        u32 parts[4];
#pragma unroll
        for (int jj = 0; jj < 4; ++jj) {
            int ca = g * 8 + 2 * jj;
            int cb = ca + 1;
            float va = lf[ca * 128 + ((wq4 ^ ((ca >> 3) ^ (ca & 7))) * 4) + wr];
            float vb = lf[cb * 128 + ((wq4 ^ ((cb >> 3) ^ (cb & 7))) * 4) + wr];
            parts[jj] = (u32)f2bf(va) | ((u32)f2bf(vb) << 16);
        }
        uint4 q;
        q.x = parts[0]; q.y = parts[1]; q.z = parts[2]; q.w = parts[3];
        *(uint4*)(dst + (size_t)w * 64 + slot * 8) = q;   // coalesced 16B/lane
    }
}

// ---- kernel 3 (fast path): conv via implicit GEMM, DMA staging ----
// v5 = v4 skeleton (48KB LDS, 3 blocks/CU, XCD swizzle, swapped MFMA, float4
// stores) + latency fixes:
//  * explicit per-(kh,ks) staging of all 12 weight fragments into registers
//    (forces a deep prefetch window the default scheduler refused at VGPR=76);
//    launch_bounds(256,3) caps VGPR ~168 so 3 blocks/CU survives.
//  * precomputed b-fragment LDS byte addresses: ks toggles byte-bit6 (XOR 64),
//    kh folds into the ds_read offset immediate (0/16384/32768).
__global__ __launch_bounds__(256, 3)
void conv_mfma_v5(const u16* __restrict__ xq, const u16* __restrict__ wq,
                  const float* __restrict__ bias, const float* __restrict__ gamma,
                  const float* __restrict__ beta, const float* __restrict__ rmean,
                  const float* __restrict__ rvar, float* __restrict__ out) {
    __shared__ u16 in_lds[3 * 128 * 64];   // 48 KB, rows h0..h0+2, swizzled layout
    __shared__ float s_scale[CO], s_shift[CO], s_bias[CO];

    const int tid = threadIdx.x;
    // bijective XCD swizzle: dispatch id D -> work id L, XCD (D&7) gets chunk of 504
    const int D = blockIdx.y * 126 + blockIdx.x;
    const int L = (D & 7) * 504 + (D >> 3);
    const int n  = L / 126;          // 0..31
    const int h0 = L - n * 126;      // 0..125

    // DMA rows h0..h0+2 (contiguous 48 KB in xq) into LDS: 12 x 1KB per wave.
    const int wv   = tid >> 6;
    const int lane = tid & 63;
    const u16* src = xq + (size_t)(n * 128 + h0) * 8192;
#pragma unroll
    for (int s = 0; s < 12; ++s) {
        int chunk = s * 4 + wv;                      // 48 chunks of 512 u16 (1 KB)
        const u16* gp = src + chunk * 512 + lane * 8;
        u16*       lp = in_lds + chunk * 512 + lane * 8;
        __builtin_amdgcn_global_load_lds(
            (const __attribute__((address_space(1))) u32*)gp,
            (__attribute__((address_space(3))) u32*)lp, 16, 0, 0);
    }

    if (tid < CO) {                                  // VALU work overlaps DMA latency
        float sc = gamma[tid] * rsqrtf(rvar[tid] + 1e-5f);
        s_scale[tid] = sc;
        s_shift[tid] = beta[tid] - rmean[tid] * sc;
        s_bias[tid]  = bias[tid];
    }

    const int li = tid & 15;          // lane & 15
    const int qd = (tid & 63) >> 4;   // quad
    const int wm = wv & 1;            // co-half
    const int wn = wv >> 1;           // pixel-half

    // precompute b-fragment LDS byte addresses (ks=0, kh=0)
    u32 baddr[4][3];
#pragma unroll
    for (int j = 0; j < 4; ++j)
#pragma unroll
        for (int kw = 0; kw < 3; ++kw) {
            int w  = wn * 64 + j * 16 + li + kw;  // input col (<=129; OOB lanes masked in epilogue)
            int s  = w & 7;
            int g0 = (qd ^ (s & 3)) + 4 * (s >> 2);
            baddr[j][kw] = (u32)(w * 128 + g0 * 16);
        }

    __syncthreads();

    f32x4 zero4 = {0.f, 0.f, 0.f, 0.f};
    f32x4 acc[4][4];
#pragma unroll
    for (int i = 0; i < 4; ++i)
#pragma unroll
        for (int j = 0; j < 4; ++j) acc[i][j] = zero4;

    // weight granule base for this lane: wg[tap*1024 + co*8 + ks*4 + qd],
    // co = wm*64 + i*16 + li  =>  base = wm*512 + li*8 + qd
    const uint4* wp = (const uint4*)wq + (wm * 512 + li * 8 + qd);
    const char*  lb = (const char*)in_lds;

    // K-loop: 3 kh x 2 ks groups; each group stages 12 A-fragments then 48 MFMAs
#pragma unroll
    for (int kh = 0; kh < 3; ++kh) {
#pragma unroll
        for (int ks = 0; ks < 2; ++ks) {
            const u32 ksx = (u32)(ks << 6);
            short8 aw[3][4];
#pragma unroll
            for (int kw = 0; kw < 3; ++kw)
#pragma unroll
                for (int i = 0; i < 4; ++i)
                    aw[kw][i] = __builtin_bit_cast(short8,
                        wp[(kh * 3 + kw) * 1024 + i * 128 + ks * 4]);
#pragma unroll
            for (int kw = 0; kw < 3; ++kw) {
                short8 b[4];
#pragma unroll
                for (int j = 0; j < 4; ++j)
                    b[j] = *(const short8*)(lb + ((baddr[j][kw] ^ ksx) + kh * 16384));
                // SWAPPED operands: A=pixels, B=weights => D row=wo, col=co
#pragma unroll
                for (int i = 0; i < 4; ++i)
#pragma unroll
                    for (int j = 0; j < 4; ++j)
                        acc[i][j] = __builtin_amdgcn_mfma_f32_16x16x32_bf16(
                            b[j], aw[kw][i], acc[i][j], 0, 0, 0);
            }
        }
    }

    // epilogue: bias + mish + BN affine; vectorized stores (lane owns 4 wo of 1 co)
    const bool al16 = ((h0 & 1) == 0);   // even row base is 16B aligned
    float* ob = out + (size_t)n * CO * (HO * WO) + (size_t)h0 * WO;
#pragma unroll
    for (int i = 0; i < 4; ++i) {
        int co = wm * 64 + i * 16 + li;
        float sc = s_scale[co], sh = s_shift[co], bs = s_bias[co];
        float* op = ob + (size_t)co * (HO * WO);
#pragma unroll
        for (int j = 0; j < 4; ++j) {
            int wo0 = wn * 64 + j * 16 + qd * 4;
            f32x4 v;
#pragma unroll
            for (int r = 0; r < 4; ++r) {
                float z  = acc[i][j][r] + bs;
                float u  = 1.0f + __expf(fminf(z, 20.0f));
                float u2 = u * u;
                float t  = __fdividef(u2 - 1.0f, u2 + 1.0f);  // tanh(softplus(z))
                v[r] = z * t * sc + sh;
            }
            if (wo0 + 3 < WO) {
                if (al16) {
                    *(f32x4*)(op + wo0) = v;
                } else {
                    float2 t0; t0.x = v[0]; t0.y = v[1];
                    float2 t1; t1.x = v[2]; t1.y = v[3];
                    *(float2*)(op + wo0)     = t0;
                    *(float2*)(op + wo0 + 2) = t1;
                }
            } else {
#pragma unroll
                for (int r = 0; r < 4; ++r)
                    if (wo0 + r < WO) op[wo0 + r] = v[r];
            }
        }
    }
}

// ---- fallback (round-1) conv: used only if ws too small for xq ----
__global__ __launch_bounds__(256, 2)
void conv_mfma(const float* __restrict__ x, const u16* __restrict__ wq,
               const float* __restrict__ bias, const float* __restrict__ gamma,
               const float* __restrict__ beta, const float* __restrict__ rmean,
               const float* __restrict__ rvar, float* __restrict__ out) {
    __shared__ u32 in_lds[3 * 130 * 32];
    __shared__ float s_scale[CO], s_shift[CO], s_bias[CO];

    const int tid = threadIdx.x;
    const int h0  = blockIdx.x;
    const int n   = blockIdx.y;

    if (tid < CO) {
        float sc = gamma[tid] * rsqrtf(rvar[tid] + 1e-5f);
        s_scale[tid] = sc;
        s_shift[tid] = beta[tid] - rmean[tid] * sc;
        s_bias[tid]  = bias[tid];
    }
    if (tid < 48) {
        int kh  = tid >> 4;
        int rem = tid & 15;
        int w   = 128 + (rem & 1);
        int g   = rem >> 1;
        uint4 z = {0u, 0u, 0u, 0u};
        *(uint4*)&in_lds[(kh * 130 + w) * 32 + ((g ^ (w & 7)) * 4)] = z;
    }
    const float* xb = x + (size_t)n * CI * HH * WW;
    for (int it = 0; it < 12; ++it) {
        int idx = it * 256 + tid;
        int w   = idx & 127;
        int g   = (idx >> 7) & 7;
        int kh  = idx >> 10;
        const float* p = xb + (g * 8) * (HH * WW) + (h0 + kh) * WW + w;
        float v[8];
#pragma unroll
        for (int j = 0; j < 8; ++j) v[j] = p[j * (HH * WW)];
        uint4 q;
        q.x = (u32)f2bf(v[0]) | ((u32)f2bf(v[1]) << 16);
        q.y = (u32)f2bf(v[2]) | ((u32)f2bf(v[3]) << 16);
        q.z = (u32)f2bf(v[4]) | ((u32)f2bf(v[5]) << 16);
        q.w = (u32)f2bf(v[6]) | ((u32)f2bf(v[7]) << 16);
        *(uint4*)&in_lds[(kh * 130 + w) * 32 + ((g ^ (w & 7)) * 4)] = q;
    }
    __syncthreads();

    const int wv = tid >> 6;
    const int li = tid & 15;
    const int qd = (tid & 63) >> 4;
    const int wm = wv & 1;
    const int wn = wv >> 1;

    f32x4 zero4 = {0.f, 0.f, 0.f, 0.f};
    f32x4 acc[4][4];
#pragma unroll
    for (int i = 0; i < 4; ++i)
#pragma unroll
        for (int j = 0; j < 4; ++j) acc[i][j] = zero4;

    const uint4* wg = (const uint4*)wq;

#pragma unroll 1
    for (int kh = 0; kh < 3; ++kh) {
#pragma unroll
        for (int kw = 0; kw < 3; ++kw) {
            const int tap = kh * 3 + kw;
#pragma unroll
            for (int ks = 0; ks < 2; ++ks) {
                short8 a[4], b[4];
#pragma unroll
                for (int i = 0; i < 4; ++i) {
                    int co = wm * 64 + i * 16 + li;
                    a[i] = __builtin_bit_cast(short8,
                        wg[tap * 1024 + co * 8 + ks * 4 + qd]);
                }
#pragma unroll
                for (int j = 0; j < 4; ++j) {
                    int w = wn * 64 + j * 16 + li + kw;
                    int g = ks * 4 + qd;
                    b[j] = *(const short8*)&in_lds[(kh * 130 + w) * 32 +
                                                   ((g ^ (w & 7)) * 4)];
                }
#pragma unroll
                for (int i = 0; i < 4; ++i)
#pragma unroll
                    for (int j = 0; j < 4; ++j)
                        acc[i][j] = __builtin_amdgcn_mfma_f32_16x16x32_bf16(
                            a[i], b[j], acc[i][j], 0, 0, 0);
            }
        }
    }

    float* ob = out + (size_t)n * CO * (HO * WO) + (size_t)h0 * WO;
#pragma unroll
    for (int j = 0; j < 4; ++j) {
        int wo = wn * 64 + j * 16 + li;
        if (wo < WO) {
#pragma unroll
            for (int i = 0; i < 4; ++i) {
#pragma unroll
                for (int r = 0; r < 4; ++r) {
                    int co  = wm * 64 + i * 16 + qd * 4 + r;
                    float z  = acc[i][j][r] + s_bias[co];
                    float u  = 1.0f + __expf(fminf(z, 20.0f));
                    float u2 = u * u;
                    float t  = __fdividef(u2 - 1.0f, u2 + 1.0f);
                    ob[(size_t)co * (HO * WO) + wo] = z * t * s_scale[co] + s_shift[co];
                }
            }
        }
    }
}

extern "C" void kernel_launch(void* const* d_in, const int* in_sizes, int n_in,
                              void* d_out, int out_size, void* d_ws, size_t ws_size,
                              hipStream_t stream) {
    const float* x     = (const float*)d_in[0];
    const float* wt    = (const float*)d_in[1];
    const float* bias  = (const float*)d_in[2];
    const float* gamma = (const float*)d_in[3];
    const float* beta  = (const float*)d_in[4];
    const float* rmean = (const float*)d_in[5];
    const float* rvar  = (const float*)d_in[6];

    const size_t XQ_BYTES = (size_t)64 * 1024 * 1024;    // 32*128*128*64*2 = 64 MiB
    const size_t WQ_BYTES = (size_t)9 * CO * CI * 2;     // 144 KiB

    if (ws_size >= XQ_BYTES + WQ_BYTES) {
        u16* xq = (u16*)d_ws;
        u16* wq = (u16*)((char*)d_ws + XQ_BYTES);
        hipLaunchKernelGGL(reorder_w, dim3(288), dim3(256), 0, stream, wt, wq);
        hipLaunchKernelGGL(prep_x, dim3(4096), dim3(256), 0, stream, x, xq);
        hipLaunchKernelGGL(conv_mfma_v5, dim3(HO, 32), dim3(256), 0, stream,
                           xq, wq, bias, gamma, beta, rmean, rvar, (float*)d_out);
    } else {
        u16* wq = (u16*)d_ws;
        hipLaunchKernelGGL(reorder_w, dim3(288), dim3(256), 0, stream, wt, wq);
        hipLaunchKernelGGL(conv_mfma, dim3(HO, 32), dim3(256), 0, stream,
                           x, wq, bias, gamma, beta, rmean, rvar, (float*)d_out);
    }
}